// Round 2
// baseline (6480.601 us; speedup 1.0000x reference)
//
#include <hip/hip_runtime.h>

#define N_NODES 100000
#define N_EDGES 1600000
#define NF 64
#define NC 10
#define NL 4
#define NG 512

// ---------------------------------------------------------------------------
// Scatter-add: aggr[dst] += x[src].  16 threads per edge, float4 per thread.
// unsafeAtomicAdd -> global_atomic_add_f32 (HW fp32 atomic, no CAS loop).
// ---------------------------------------------------------------------------
__global__ void scatter_kernel(const float* __restrict__ x,
                               const int* __restrict__ ei,
                               float* __restrict__ aggr) {
    long tid = (long)blockIdx.x * blockDim.x + threadIdx.x;
    int e = (int)(tid >> 4);
    if (e >= N_EDGES) return;
    int f = ((int)tid & 15) * 4;
    int s = ei[e];
    int d = ei[N_EDGES + e];
    const float4 v = *reinterpret_cast<const float4*>(x + (long)s * NF + f);
    float* a = aggr + (long)d * NF + f;
    unsafeAtomicAdd(a + 0, v.x);
    unsafeAtomicAdd(a + 1, v.y);
    unsafeAtomicAdd(a + 2, v.z);
    unsafeAtomicAdd(a + 3, v.w);
}

// ---------------------------------------------------------------------------
// MLP pass 1: tmp = relu((x + aggr) @ W1)   [N,64]x[64,128] -> [N,128]
// Thread per node. W1 addresses are wave-uniform -> scalarized s_loads.
// ---------------------------------------------------------------------------
__global__ void mlp1_kernel(const float* __restrict__ xin,
                            const float* __restrict__ aggr,
                            const float* __restrict__ W1,
                            float* __restrict__ tmp) {
    int i = blockIdx.x * blockDim.x + threadIdx.x;
    if (i >= N_NODES) return;
    float h[NF];
    const float4* xi = reinterpret_cast<const float4*>(xin + (long)i * NF);
    const float4* ai = reinterpret_cast<const float4*>(aggr + (long)i * NF);
#pragma unroll
    for (int q = 0; q < NF / 4; q++) {
        float4 a = xi[q], b = ai[q];
        h[4 * q + 0] = a.x + b.x;
        h[4 * q + 1] = a.y + b.y;
        h[4 * q + 2] = a.z + b.z;
        h[4 * q + 3] = a.w + b.w;
    }
    float4* to = reinterpret_cast<float4*>(tmp + (long)i * 2 * NF);
    for (int c = 0; c < 2 * NF; c += 4) {
        float acc0 = 0.f, acc1 = 0.f, acc2 = 0.f, acc3 = 0.f;
#pragma unroll
        for (int k = 0; k < NF; k++) {
            const float4 w = *reinterpret_cast<const float4*>(W1 + k * 2 * NF + c);
            acc0 += h[k] * w.x;
            acc1 += h[k] * w.y;
            acc2 += h[k] * w.z;
            acc3 += h[k] * w.w;
        }
        to[c / 4] = float4{fmaxf(acc0, 0.f), fmaxf(acc1, 0.f),
                           fmaxf(acc2, 0.f), fmaxf(acc3, 0.f)};
    }
}

// ---------------------------------------------------------------------------
// MLP pass 2: xout = relu(tmp @ W2)   [N,128]x[128,64] -> [N,64]
// ---------------------------------------------------------------------------
__global__ void mlp2_kernel(const float* __restrict__ tmp,
                            const float* __restrict__ W2,
                            float* __restrict__ xout) {
    int i = blockIdx.x * blockDim.x + threadIdx.x;
    if (i >= N_NODES) return;
    float t[2 * NF];
    const float4* ti = reinterpret_cast<const float4*>(tmp + (long)i * 2 * NF);
#pragma unroll
    for (int q = 0; q < 2 * NF / 4; q++) {
        float4 a = ti[q];
        t[4 * q + 0] = a.x;
        t[4 * q + 1] = a.y;
        t[4 * q + 2] = a.z;
        t[4 * q + 3] = a.w;
    }
    float4* xo = reinterpret_cast<float4*>(xout + (long)i * NF);
    for (int c = 0; c < NF; c += 4) {
        float acc0 = 0.f, acc1 = 0.f, acc2 = 0.f, acc3 = 0.f;
#pragma unroll
        for (int k = 0; k < 2 * NF; k++) {
            const float4 w = *reinterpret_cast<const float4*>(W2 + k * NF + c);
            acc0 += t[k] * w.x;
            acc1 += t[k] * w.y;
            acc2 += t[k] * w.z;
            acc3 += t[k] * w.w;
        }
        xo[c / 4] = float4{fmaxf(acc0, 0.f), fmaxf(acc1, 0.f),
                           fmaxf(acc2, 0.f), fmaxf(acc3, 0.f)};
    }
}

// ---------------------------------------------------------------------------
// Global add-pool: pooled[batch[i]] += x[i].  16 threads/node, float4 each.
// ---------------------------------------------------------------------------
__global__ void pool_kernel(const float* __restrict__ x,
                            const int* __restrict__ batch,
                            float* __restrict__ pooled) {
    long tid = (long)blockIdx.x * blockDim.x + threadIdx.x;
    int i = (int)(tid >> 4);
    if (i >= N_NODES) return;
    int f = ((int)tid & 15) * 4;
    int g = batch[i];
    const float4 v = *reinterpret_cast<const float4*>(x + (long)i * NF + f);
    float* p = pooled + (long)g * NF + f;
    unsafeAtomicAdd(p + 0, v.x);
    unsafeAtomicAdd(p + 1, v.y);
    unsafeAtomicAdd(p + 2, v.z);
    unsafeAtomicAdd(p + 3, v.w);
}

// ---------------------------------------------------------------------------
// Head: logits = pooled @ fcW + fcb; out = log_softmax(logits).  Thread/graph.
// ---------------------------------------------------------------------------
__global__ void head_kernel(const float* __restrict__ pooled,
                            const float* __restrict__ fcW,
                            const float* __restrict__ fcb,
                            float* __restrict__ out) {
    int g = blockIdx.x * blockDim.x + threadIdx.x;
    if (g >= NG) return;
    float p[NF];
    const float4* pi = reinterpret_cast<const float4*>(pooled + (long)g * NF);
#pragma unroll
    for (int q = 0; q < NF / 4; q++) {
        float4 a = pi[q];
        p[4 * q + 0] = a.x;
        p[4 * q + 1] = a.y;
        p[4 * q + 2] = a.z;
        p[4 * q + 3] = a.w;
    }
    float lg[NC];
#pragma unroll
    for (int c = 0; c < NC; c++) {
        float acc = fcb[c];
#pragma unroll
        for (int k = 0; k < NF; k++) acc += p[k] * fcW[k * NC + c];
        lg[c] = acc;
    }
    float m = lg[0];
#pragma unroll
    for (int c = 1; c < NC; c++) m = fmaxf(m, lg[c]);
    float s = 0.f;
#pragma unroll
    for (int c = 0; c < NC; c++) s += expf(lg[c] - m);
    float ls = logf(s);
#pragma unroll
    for (int c = 0; c < NC; c++) out[(long)g * NC + c] = lg[c] - m - ls;
}

extern "C" void kernel_launch(void* const* d_in, const int* in_sizes, int n_in,
                              void* d_out, int out_size, void* d_ws, size_t ws_size,
                              hipStream_t stream) {
    const float* x   = (const float*)d_in[0];
    const float* W1  = (const float*)d_in[1];
    const float* W2  = (const float*)d_in[2];
    const float* fcW = (const float*)d_in[3];
    const float* fcb = (const float*)d_in[4];
    const int* ei    = (const int*)d_in[5];
    const int* batch = (const int*)d_in[6];
    float* out = (float*)d_out;

    // Workspace layout (floats):
    //   A [N,64] | B [N,64] | T [N,128] | pooled [512,64]   -> ~102.6 MB
    float* A = (float*)d_ws;
    float* B = A + (size_t)N_NODES * NF;
    float* T = B + (size_t)N_NODES * NF;
    float* pooled = T + (size_t)N_NODES * 2 * NF;

    const float* cur = x;
    for (int l = 0; l < NL; l++) {
        // aggr buffer: the node buffer not currently holding `cur`
        float* aggr = (cur == (const float*)A) ? B : ((cur == (const float*)B) ? A : B);
        float* outb = (l == 0) ? A : aggr;  // safe: aggr consumed before mlp2 writes

        hipMemsetAsync(aggr, 0, (size_t)N_NODES * NF * sizeof(float), stream);
        {
            long total = (long)N_EDGES * 16;
            int blocks = (int)((total + 255) / 256);
            scatter_kernel<<<blocks, 256, 0, stream>>>(cur, ei, aggr);
        }
        mlp1_kernel<<<(N_NODES + 255) / 256, 256, 0, stream>>>(
            cur, aggr, W1 + (size_t)l * NF * 2 * NF, T);
        mlp2_kernel<<<(N_NODES + 255) / 256, 256, 0, stream>>>(
            T, W2 + (size_t)l * 2 * NF * NF, outb);
        cur = outb;
    }

    hipMemsetAsync(pooled, 0, (size_t)NG * NF * sizeof(float), stream);
    {
        long total = (long)N_NODES * 16;
        int blocks = (int)((total + 255) / 256);
        pool_kernel<<<blocks, 256, 0, stream>>>(cur, batch, pooled);
    }
    head_kernel<<<(NG + 255) / 256, 256, 0, stream>>>(pooled, fcW, fcb, out);
}

// Round 3
// 1701.665 us; speedup vs baseline: 3.8084x; 3.8084x over previous
//
#include <hip/hip_runtime.h>

#define N_NODES 100000
#define N_EDGES 1600000
#define NF 64
#define NC 10
#define NL 4
#define NG 512

#define SCAN_THREADS 1024
#define SCAN_CHUNK 98  // ceil(100000/1024)

// ---------------------------------------------------------------------------
// CSR build step 1: histogram of dst. counts[] pre-zeroed by memset.
// ---------------------------------------------------------------------------
__global__ void hist_kernel(const int* __restrict__ ei, int* __restrict__ counts) {
    int e = blockIdx.x * blockDim.x + threadIdx.x;
    if (e >= N_EDGES) return;
    atomicAdd(&counts[ei[N_EDGES + e]], 1);
}

// ---------------------------------------------------------------------------
// CSR build step 2a: per-thread partial sums over contiguous chunks.
// ---------------------------------------------------------------------------
__global__ void scan1_kernel(const int* __restrict__ counts, int* __restrict__ partial) {
    int t = blockIdx.x * blockDim.x + threadIdx.x;
    if (t >= SCAN_THREADS) return;
    int beg = t * SCAN_CHUNK, end = min(beg + SCAN_CHUNK, N_NODES);
    int s = 0;
    for (int i = beg; i < end; i++) s += counts[i];
    partial[t] = s;
}

// ---------------------------------------------------------------------------
// CSR build step 2b: exclusive scan of the 1024 partials (single block).
// ---------------------------------------------------------------------------
__global__ void scan2_kernel(int* __restrict__ partial) {
    __shared__ int buf[SCAN_THREADS];
    int t = threadIdx.x;
    int v = partial[t];
    buf[t] = v;
    __syncthreads();
    for (int off = 1; off < SCAN_THREADS; off <<= 1) {
        int u = (t >= off) ? buf[t - off] : 0;
        __syncthreads();
        buf[t] += u;
        __syncthreads();
    }
    partial[t] = buf[t] - v;  // exclusive
}

// ---------------------------------------------------------------------------
// CSR build step 2c: expand to row_start / cursor.
// ---------------------------------------------------------------------------
__global__ void scan3_kernel(const int* __restrict__ counts,
                             const int* __restrict__ partial,
                             int* __restrict__ row_start,
                             int* __restrict__ cursor) {
    int t = blockIdx.x * blockDim.x + threadIdx.x;
    if (t >= SCAN_THREADS) return;
    int beg = t * SCAN_CHUNK, end = min(beg + SCAN_CHUNK, N_NODES);
    int run = partial[t];
    for (int i = beg; i < end; i++) {
        row_start[i] = run;
        cursor[i] = run;
        run += counts[i];
    }
    if (t == SCAN_THREADS - 1) row_start[N_NODES] = N_EDGES;
}

// ---------------------------------------------------------------------------
// CSR build step 3: fill csr_src (counting-sort permutation).
// ---------------------------------------------------------------------------
__global__ void fill_kernel(const int* __restrict__ ei,
                            int* __restrict__ cursor,
                            int* __restrict__ csr_src) {
    int e = blockIdx.x * blockDim.x + threadIdx.x;
    if (e >= N_EDGES) return;
    int s = ei[e];
    int d = ei[N_EDGES + e];
    int pos = atomicAdd(&cursor[d], 1);
    csr_src[pos] = s;
}

// ---------------------------------------------------------------------------
// Atomic-free aggregation (gather): h[i] = x[i] + sum_{j->i} x[j].
// 16 threads per node, float4 per thread; x rows are L2/L3-resident.
// ---------------------------------------------------------------------------
__global__ void gather_kernel(const float* __restrict__ x,
                              const int* __restrict__ row_start,
                              const int* __restrict__ csr_src,
                              float* __restrict__ h) {
    long tid = (long)blockIdx.x * blockDim.x + threadIdx.x;
    int i = (int)(tid >> 4);
    if (i >= N_NODES) return;
    int f4 = (int)tid & 15;
    const float4* x4 = reinterpret_cast<const float4*>(x);
    float4 acc = x4[(long)i * 16 + f4];  // (1+eps)*x_i, eps=0
    int beg = row_start[i], end = row_start[i + 1];
    for (int e = beg; e < end; e++) {
        int s = csr_src[e];
        float4 v = x4[(long)s * 16 + f4];
        acc.x += v.x; acc.y += v.y; acc.z += v.z; acc.w += v.w;
    }
    reinterpret_cast<float4*>(h)[(long)i * 16 + f4] = acc;
}

// ---------------------------------------------------------------------------
// MLP pass 1: tmp = relu(h @ W1)   [N,64]x[64,128] -> [N,128]
// ---------------------------------------------------------------------------
__global__ void mlp1_kernel(const float* __restrict__ hin,
                            const float* __restrict__ W1,
                            float* __restrict__ tmp) {
    int i = blockIdx.x * blockDim.x + threadIdx.x;
    if (i >= N_NODES) return;
    float h[NF];
    const float4* hi = reinterpret_cast<const float4*>(hin + (long)i * NF);
#pragma unroll
    for (int q = 0; q < NF / 4; q++) {
        float4 a = hi[q];
        h[4 * q + 0] = a.x; h[4 * q + 1] = a.y;
        h[4 * q + 2] = a.z; h[4 * q + 3] = a.w;
    }
    float4* to = reinterpret_cast<float4*>(tmp + (long)i * 2 * NF);
    for (int c = 0; c < 2 * NF; c += 4) {
        float acc0 = 0.f, acc1 = 0.f, acc2 = 0.f, acc3 = 0.f;
#pragma unroll
        for (int k = 0; k < NF; k++) {
            const float4 w = *reinterpret_cast<const float4*>(W1 + k * 2 * NF + c);
            acc0 += h[k] * w.x; acc1 += h[k] * w.y;
            acc2 += h[k] * w.z; acc3 += h[k] * w.w;
        }
        to[c / 4] = float4{fmaxf(acc0, 0.f), fmaxf(acc1, 0.f),
                           fmaxf(acc2, 0.f), fmaxf(acc3, 0.f)};
    }
}

// ---------------------------------------------------------------------------
// MLP pass 2: xout = relu(tmp @ W2)   [N,128]x[128,64] -> [N,64]
// ---------------------------------------------------------------------------
__global__ void mlp2_kernel(const float* __restrict__ tmp,
                            const float* __restrict__ W2,
                            float* __restrict__ xout) {
    int i = blockIdx.x * blockDim.x + threadIdx.x;
    if (i >= N_NODES) return;
    float t[2 * NF];
    const float4* ti = reinterpret_cast<const float4*>(tmp + (long)i * 2 * NF);
#pragma unroll
    for (int q = 0; q < 2 * NF / 4; q++) {
        float4 a = ti[q];
        t[4 * q + 0] = a.x; t[4 * q + 1] = a.y;
        t[4 * q + 2] = a.z; t[4 * q + 3] = a.w;
    }
    float4* xo = reinterpret_cast<float4*>(xout + (long)i * NF);
    for (int c = 0; c < NF; c += 4) {
        float acc0 = 0.f, acc1 = 0.f, acc2 = 0.f, acc3 = 0.f;
#pragma unroll
        for (int k = 0; k < 2 * NF; k++) {
            const float4 w = *reinterpret_cast<const float4*>(W2 + k * NF + c);
            acc0 += t[k] * w.x; acc1 += t[k] * w.y;
            acc2 += t[k] * w.z; acc3 += t[k] * w.w;
        }
        xo[c / 4] = float4{fmaxf(acc0, 0.f), fmaxf(acc1, 0.f),
                           fmaxf(acc2, 0.f), fmaxf(acc3, 0.f)};
    }
}

// ---------------------------------------------------------------------------
// Global add-pool over sorted batch: register accumulation, flush on graph
// change. Thread owns feature-quad f4 of 16 consecutive nodes.
// ---------------------------------------------------------------------------
__global__ void pool_kernel(const float* __restrict__ x,
                            const int* __restrict__ batch,
                            float* __restrict__ pooled) {
    int tid = blockIdx.x * blockDim.x + threadIdx.x;
    int chunk = tid >> 4;
    int base = chunk * 16;
    if (base >= N_NODES) return;
    int f4 = tid & 15;
    int endn = min(base + 16, N_NODES);
    const float4* x4 = reinterpret_cast<const float4*>(x);
    float4 acc{0.f, 0.f, 0.f, 0.f};
    int curg = batch[base];
    for (int i = base; i < endn; i++) {
        int g = batch[i];
        if (g != curg) {
            float* p = pooled + (long)curg * NF + f4 * 4;
            unsafeAtomicAdd(p + 0, acc.x); unsafeAtomicAdd(p + 1, acc.y);
            unsafeAtomicAdd(p + 2, acc.z); unsafeAtomicAdd(p + 3, acc.w);
            acc = float4{0.f, 0.f, 0.f, 0.f};
            curg = g;
        }
        float4 v = x4[(long)i * 16 + f4];
        acc.x += v.x; acc.y += v.y; acc.z += v.z; acc.w += v.w;
    }
    float* p = pooled + (long)curg * NF + f4 * 4;
    unsafeAtomicAdd(p + 0, acc.x); unsafeAtomicAdd(p + 1, acc.y);
    unsafeAtomicAdd(p + 2, acc.z); unsafeAtomicAdd(p + 3, acc.w);
}

// ---------------------------------------------------------------------------
// Head: logits = pooled @ fcW + fcb; out = log_softmax(logits).
// ---------------------------------------------------------------------------
__global__ void head_kernel(const float* __restrict__ pooled,
                            const float* __restrict__ fcW,
                            const float* __restrict__ fcb,
                            float* __restrict__ out) {
    int g = blockIdx.x * blockDim.x + threadIdx.x;
    if (g >= NG) return;
    float p[NF];
    const float4* pi = reinterpret_cast<const float4*>(pooled + (long)g * NF);
#pragma unroll
    for (int q = 0; q < NF / 4; q++) {
        float4 a = pi[q];
        p[4 * q + 0] = a.x; p[4 * q + 1] = a.y;
        p[4 * q + 2] = a.z; p[4 * q + 3] = a.w;
    }
    float lg[NC];
#pragma unroll
    for (int c = 0; c < NC; c++) {
        float acc = fcb[c];
#pragma unroll
        for (int k = 0; k < NF; k++) acc += p[k] * fcW[k * NC + c];
        lg[c] = acc;
    }
    float m = lg[0];
#pragma unroll
    for (int c = 1; c < NC; c++) m = fmaxf(m, lg[c]);
    float s = 0.f;
#pragma unroll
    for (int c = 0; c < NC; c++) s += expf(lg[c] - m);
    float ls = logf(s);
#pragma unroll
    for (int c = 0; c < NC; c++) out[(long)g * NC + c] = lg[c] - m - ls;
}

extern "C" void kernel_launch(void* const* d_in, const int* in_sizes, int n_in,
                              void* d_out, int out_size, void* d_ws, size_t ws_size,
                              hipStream_t stream) {
    const float* x   = (const float*)d_in[0];
    const float* W1  = (const float*)d_in[1];
    const float* W2  = (const float*)d_in[2];
    const float* fcW = (const float*)d_in[3];
    const float* fcb = (const float*)d_in[4];
    const int* ei    = (const int*)d_in[5];
    const int* batch = (const int*)d_in[6];
    float* out = (float*)d_out;

    // Workspace layout:
    //   floats: A [N,64] | H [N,64] | T [N,128] | pooled [512,64]  (~102.5 MB)
    //   ints:   counts[N] | row_start[N+1] | cursor[N] | partial[1024]
    //           | csr_src[E]                                        (~7.6 MB)
    float* A = (float*)d_ws;
    float* H = A + (size_t)N_NODES * NF;
    float* T = H + (size_t)N_NODES * NF;
    float* pooled = T + (size_t)N_NODES * 2 * NF;
    int* counts    = (int*)(pooled + (size_t)NG * NF);
    int* row_start = counts + N_NODES;
    int* cursor    = row_start + (N_NODES + 1);
    int* partial   = cursor + N_NODES;
    int* csr_src   = partial + SCAN_THREADS;

    // ---- CSR build (counting sort by dst), once per call ----
    hipMemsetAsync(counts, 0, N_NODES * sizeof(int), stream);
    hist_kernel<<<(N_EDGES + 255) / 256, 256, 0, stream>>>(ei, counts);
    scan1_kernel<<<SCAN_THREADS / 256, 256, 0, stream>>>(counts, partial);
    scan2_kernel<<<1, SCAN_THREADS, 0, stream>>>(partial);
    scan3_kernel<<<SCAN_THREADS / 256, 256, 0, stream>>>(counts, partial,
                                                         row_start, cursor);
    fill_kernel<<<(N_EDGES + 255) / 256, 256, 0, stream>>>(ei, cursor, csr_src);

    // ---- 4 GIN layers ----
    const float* cur = x;
    for (int l = 0; l < NL; l++) {
        {
            long total = (long)N_NODES * 16;
            int blocks = (int)((total + 255) / 256);
            gather_kernel<<<blocks, 256, 0, stream>>>(cur, row_start, csr_src, H);
        }
        mlp1_kernel<<<(N_NODES + 255) / 256, 256, 0, stream>>>(
            H, W1 + (size_t)l * NF * 2 * NF, T);
        mlp2_kernel<<<(N_NODES + 255) / 256, 256, 0, stream>>>(
            T, W2 + (size_t)l * 2 * NF * NF, A);
        cur = A;  // gather fully consumes cur before mlp2 overwrites A
    }

    // ---- pool + head ----
    hipMemsetAsync(pooled, 0, (size_t)NG * NF * sizeof(float), stream);
    pool_kernel<<<(N_NODES + 255) / 256, 256, 0, stream>>>(cur, batch, pooled);
    head_kernel<<<(NG + 255) / 256, 256, 0, stream>>>(pooled, fcW, fcb, out);
}

// Round 8
// 869.760 us; speedup vs baseline: 7.4510x; 1.9565x over previous
//
#include <hip/hip_runtime.h>

#define N_NODES 100000
#define N_EDGES 1600000
#define NF 64
#define NC 10
#define NL 4
#define NG 512

#define SCAN_THREADS 1024
#define SCAN_CHUNK 98  // ceil(100000/1024)

// ---------------------------------------------------------------------------
// CSR build step 1: histogram of dst. counts[] pre-zeroed by memset.
// ---------------------------------------------------------------------------
__global__ void hist_kernel(const int* __restrict__ ei, int* __restrict__ counts) {
    int e = blockIdx.x * blockDim.x + threadIdx.x;
    if (e >= N_EDGES) return;
    atomicAdd(&counts[ei[N_EDGES + e]], 1);
}

__global__ void scan1_kernel(const int* __restrict__ counts, int* __restrict__ partial) {
    int t = blockIdx.x * blockDim.x + threadIdx.x;
    if (t >= SCAN_THREADS) return;
    int beg = t * SCAN_CHUNK, end = min(beg + SCAN_CHUNK, N_NODES);
    int s = 0;
    for (int i = beg; i < end; i++) s += counts[i];
    partial[t] = s;
}

__global__ void scan2_kernel(int* __restrict__ partial) {
    __shared__ int buf[SCAN_THREADS];
    int t = threadIdx.x;
    int v = partial[t];
    buf[t] = v;
    __syncthreads();
    for (int off = 1; off < SCAN_THREADS; off <<= 1) {
        int u = (t >= off) ? buf[t - off] : 0;
        __syncthreads();
        buf[t] += u;
        __syncthreads();
    }
    partial[t] = buf[t] - v;  // exclusive
}

__global__ void scan3_kernel(const int* __restrict__ counts,
                             const int* __restrict__ partial,
                             int* __restrict__ row_start,
                             int* __restrict__ cursor) {
    int t = blockIdx.x * blockDim.x + threadIdx.x;
    if (t >= SCAN_THREADS) return;
    int beg = t * SCAN_CHUNK, end = min(beg + SCAN_CHUNK, N_NODES);
    int run = partial[t];
    for (int i = beg; i < end; i++) {
        row_start[i] = run;
        cursor[i] = run;
        run += counts[i];
    }
    if (t == SCAN_THREADS - 1) row_start[N_NODES] = N_EDGES;
}

__global__ void fill_kernel(const int* __restrict__ ei,
                            int* __restrict__ cursor,
                            int* __restrict__ csr_src) {
    int e = blockIdx.x * blockDim.x + threadIdx.x;
    if (e >= N_EDGES) return;
    int s = ei[e];
    int d = ei[N_EDGES + e];
    int pos = atomicAdd(&cursor[d], 1);
    csr_src[pos] = s;
}

// ---------------------------------------------------------------------------
// Atomic-free aggregation (gather): h[i] = x[i] + sum_{j->i} x[j].
// 16 threads per node, float4 per thread; x rows are L2/L3-resident.
// ---------------------------------------------------------------------------
__global__ void gather_kernel(const float* __restrict__ x,
                              const int* __restrict__ row_start,
                              const int* __restrict__ csr_src,
                              float* __restrict__ h) {
    long tid = (long)blockIdx.x * blockDim.x + threadIdx.x;
    int i = (int)(tid >> 4);
    if (i >= N_NODES) return;
    int f4 = (int)tid & 15;
    const float4* x4 = reinterpret_cast<const float4*>(x);
    float4 acc = x4[(long)i * 16 + f4];  // (1+eps)*x_i, eps=0
    int beg = row_start[i], end = row_start[i + 1];
    for (int e = beg; e < end; e++) {
        int s = csr_src[e];
        float4 v = x4[(long)s * 16 + f4];
        acc.x += v.x; acc.y += v.y; acc.z += v.z; acc.w += v.w;
    }
    reinterpret_cast<float4*>(h)[(long)i * 16 + f4] = acc;
}

// ---------------------------------------------------------------------------
// LDS-tiled MLP GEMM: out[64-node tile] = relu(in @ W).
// K in {64,128}, NOUT in {128,64}. 256 threads; thread = (tx: 16 col-groups,
// ty: 16 node-groups of 4). Register block: 4 nodes x (NOUT/16) cols.
// A-tile padded (+4) to break stride-K bank aliasing; W reads are float4
// with <=2-way aliasing (free). No scratch spills (acc <= 32 floats).
// ---------------------------------------------------------------------------
template <int K, int NOUT>
__global__ __launch_bounds__(256) void mlp_tiled(const float* __restrict__ in,
                                                 const float* __restrict__ W,
                                                 float* __restrict__ outp,
                                                 int n_nodes) {
    constexpr int PAD = 4;
    constexpr int CG = NOUT / 64;  // float4 col-groups per thread (2 or 1)
    __shared__ float As[64][K + PAD];
    __shared__ float Ws[K][NOUT];

    int tid = threadIdx.x;
    int base = blockIdx.x * 64;

    // ---- stage A tile (coalesced float4, padded LDS rows stay 16B-aligned)
    const float4* in4 = reinterpret_cast<const float4*>(in);
    for (int q = tid; q < 64 * (K / 4); q += 256) {
        int row = q / (K / 4), c4 = q % (K / 4);
        int gr = base + row;
        float4 v = float4{0.f, 0.f, 0.f, 0.f};
        if (gr < n_nodes) v = in4[(long)gr * (K / 4) + c4];
        *reinterpret_cast<float4*>(&As[row][c4 * 4]) = v;
    }
    // ---- stage W (row-major contiguous)
    const float4* W4 = reinterpret_cast<const float4*>(W);
    float4* Ws4 = reinterpret_cast<float4*>(&Ws[0][0]);
    for (int q = tid; q < K * NOUT / 4; q += 256) Ws4[q] = W4[q];
    __syncthreads();

    int tx = tid & 15, ty = tid >> 4;
    float acc[4][CG * 4];
#pragma unroll
    for (int i = 0; i < 4; i++)
#pragma unroll
        for (int c = 0; c < CG * 4; c++) acc[i][c] = 0.f;

    for (int k4 = 0; k4 < K / 4; k4++) {
        float4 a[4];
#pragma unroll
        for (int i = 0; i < 4; i++)
            a[i] = *reinterpret_cast<const float4*>(&As[ty * 4 + i][k4 * 4]);
#pragma unroll
        for (int kk = 0; kk < 4; kk++) {
            int k = k4 * 4 + kk;
#pragma unroll
            for (int g = 0; g < CG; g++) {
                float4 w = *reinterpret_cast<const float4*>(&Ws[k][g * 64 + tx * 4]);
#pragma unroll
                for (int i = 0; i < 4; i++) {
                    float av = (kk == 0) ? a[i].x : (kk == 1) ? a[i].y
                             : (kk == 2) ? a[i].z : a[i].w;
                    acc[i][g * 4 + 0] += av * w.x;
                    acc[i][g * 4 + 1] += av * w.y;
                    acc[i][g * 4 + 2] += av * w.z;
                    acc[i][g * 4 + 3] += av * w.w;
                }
            }
        }
    }

    // ---- relu + store (coalesced float4 per col-group)
#pragma unroll
    for (int i = 0; i < 4; i++) {
        int gr = base + ty * 4 + i;
        if (gr >= n_nodes) continue;
#pragma unroll
        for (int g = 0; g < CG; g++) {
            float4 o;
            o.x = fmaxf(acc[i][g * 4 + 0], 0.f);
            o.y = fmaxf(acc[i][g * 4 + 1], 0.f);
            o.z = fmaxf(acc[i][g * 4 + 2], 0.f);
            o.w = fmaxf(acc[i][g * 4 + 3], 0.f);
            *reinterpret_cast<float4*>(outp + (long)gr * NOUT + g * 64 + tx * 4) = o;
        }
    }
}

// ---------------------------------------------------------------------------
// Global add-pool over sorted batch: register accumulation, flush on graph
// change. Thread owns feature-quad f4 of 16 consecutive nodes.
// ---------------------------------------------------------------------------
__global__ void pool_kernel(const float* __restrict__ x,
                            const int* __restrict__ batch,
                            float* __restrict__ pooled) {
    int tid = blockIdx.x * blockDim.x + threadIdx.x;
    int chunk = tid >> 4;
    int base = chunk * 16;
    if (base >= N_NODES) return;
    int f4 = tid & 15;
    int endn = min(base + 16, N_NODES);
    const float4* x4 = reinterpret_cast<const float4*>(x);
    float4 acc{0.f, 0.f, 0.f, 0.f};
    int curg = batch[base];
    for (int i = base; i < endn; i++) {
        int g = batch[i];
        if (g != curg) {
            float* p = pooled + (long)curg * NF + f4 * 4;
            unsafeAtomicAdd(p + 0, acc.x); unsafeAtomicAdd(p + 1, acc.y);
            unsafeAtomicAdd(p + 2, acc.z); unsafeAtomicAdd(p + 3, acc.w);
            acc = float4{0.f, 0.f, 0.f, 0.f};
            curg = g;
        }
        float4 v = x4[(long)i * 16 + f4];
        acc.x += v.x; acc.y += v.y; acc.z += v.z; acc.w += v.w;
    }
    float* p = pooled + (long)curg * NF + f4 * 4;
    unsafeAtomicAdd(p + 0, acc.x); unsafeAtomicAdd(p + 1, acc.y);
    unsafeAtomicAdd(p + 2, acc.z); unsafeAtomicAdd(p + 3, acc.w);
}

// ---------------------------------------------------------------------------
// Head: logits = pooled @ fcW + fcb; out = log_softmax(logits).
// ---------------------------------------------------------------------------
__global__ void head_kernel(const float* __restrict__ pooled,
                            const float* __restrict__ fcW,
                            const float* __restrict__ fcb,
                            float* __restrict__ out) {
    int g = blockIdx.x * blockDim.x + threadIdx.x;
    if (g >= NG) return;
    float p[NF];
    const float4* pi = reinterpret_cast<const float4*>(pooled + (long)g * NF);
#pragma unroll
    for (int q = 0; q < NF / 4; q++) {
        float4 a = pi[q];
        p[4 * q + 0] = a.x; p[4 * q + 1] = a.y;
        p[4 * q + 2] = a.z; p[4 * q + 3] = a.w;
    }
    float lg[NC];
#pragma unroll
    for (int c = 0; c < NC; c++) {
        float acc = fcb[c];
#pragma unroll
        for (int k = 0; k < NF; k++) acc += p[k] * fcW[k * NC + c];
        lg[c] = acc;
    }
    float m = lg[0];
#pragma unroll
    for (int c = 1; c < NC; c++) m = fmaxf(m, lg[c]);
    float s = 0.f;
#pragma unroll
    for (int c = 0; c < NC; c++) s += expf(lg[c] - m);
    float ls = logf(s);
#pragma unroll
    for (int c = 0; c < NC; c++) out[(long)g * NC + c] = lg[c] - m - ls;
}

extern "C" void kernel_launch(void* const* d_in, const int* in_sizes, int n_in,
                              void* d_out, int out_size, void* d_ws, size_t ws_size,
                              hipStream_t stream) {
    const float* x   = (const float*)d_in[0];
    const float* W1  = (const float*)d_in[1];
    const float* W2  = (const float*)d_in[2];
    const float* fcW = (const float*)d_in[3];
    const float* fcb = (const float*)d_in[4];
    const int* ei    = (const int*)d_in[5];
    const int* batch = (const int*)d_in[6];
    float* out = (float*)d_out;

    // Workspace layout:
    //   floats: A [N,64] | H [N,64] | T [N,128] | pooled [512,64]  (~102.5 MB)
    //   ints:   counts[N] | row_start[N+1] | cursor[N] | partial[1024]
    //           | csr_src[E]                                        (~7.6 MB)
    float* A = (float*)d_ws;
    float* H = A + (size_t)N_NODES * NF;
    float* T = H + (size_t)N_NODES * NF;
    float* pooled = T + (size_t)N_NODES * 2 * NF;
    int* counts    = (int*)(pooled + (size_t)NG * NF);
    int* row_start = counts + N_NODES;
    int* cursor    = row_start + (N_NODES + 1);
    int* partial   = cursor + N_NODES;
    int* csr_src   = partial + SCAN_THREADS;

    // ---- CSR build (counting sort by dst), once per call ----
    hipMemsetAsync(counts, 0, N_NODES * sizeof(int), stream);
    hist_kernel<<<(N_EDGES + 255) / 256, 256, 0, stream>>>(ei, counts);
    scan1_kernel<<<SCAN_THREADS / 256, 256, 0, stream>>>(counts, partial);
    scan2_kernel<<<1, SCAN_THREADS, 0, stream>>>(partial);
    scan3_kernel<<<SCAN_THREADS / 256, 256, 0, stream>>>(counts, partial,
                                                         row_start, cursor);
    fill_kernel<<<(N_EDGES + 255) / 256, 256, 0, stream>>>(ei, cursor, csr_src);

    // ---- 4 GIN layers ----
    const int mlp_blocks = (N_NODES + 63) / 64;
    const float* cur = x;
    for (int l = 0; l < NL; l++) {
        {
            long total = (long)N_NODES * 16;
            int blocks = (int)((total + 255) / 256);
            gather_kernel<<<blocks, 256, 0, stream>>>(cur, row_start, csr_src, H);
        }
        mlp_tiled<NF, 2 * NF><<<mlp_blocks, 256, 0, stream>>>(
            H, W1 + (size_t)l * NF * 2 * NF, T, N_NODES);
        mlp_tiled<2 * NF, NF><<<mlp_blocks, 256, 0, stream>>>(
            T, W2 + (size_t)l * 2 * NF * NF, A, N_NODES);
        cur = A;  // gather fully consumes cur before mlp2 overwrites A
    }

    // ---- pool + head ----
    hipMemsetAsync(pooled, 0, (size_t)NG * NF * sizeof(float), stream);
    pool_kernel<<<(N_NODES + 255) / 256, 256, 0, stream>>>(cur, batch, pooled);
    head_kernel<<<(NG + 255) / 256, 256, 0, stream>>>(pooled, fcW, fcb, out);
}

// Round 10
// 580.848 us; speedup vs baseline: 11.1571x; 1.4974x over previous
//
#include <hip/hip_runtime.h>

#define N_NODES 100000
#define N_EDGES 1600000
#define NF 64
#define NC 10
#define NL 4
#define NG 512

#define NB 782        // dst buckets: 128 nodes each (782*128 = 100096 >= N)
#define EPB 8192      // edges per block in bucket passes

// ---------------------------------------------------------------------------
// Bucket pass 0: per-block LDS histogram of dst>>7 -> global bucket_cnt.
// ---------------------------------------------------------------------------
__global__ void bhist_kernel(const int* __restrict__ ei, int* __restrict__ bucket_cnt) {
    __shared__ int l[NB];
    for (int j = threadIdx.x; j < NB; j += 256) l[j] = 0;
    __syncthreads();
    long base = (long)blockIdx.x * EPB;
    for (int k = threadIdx.x; k < EPB; k += 256) {
        long e = base + k;
        if (e < N_EDGES) atomicAdd(&l[ei[N_EDGES + e] >> 7], 1);
    }
    __syncthreads();
    for (int j = threadIdx.x; j < NB; j += 256)
        if (l[j]) atomicAdd(&bucket_cnt[j], l[j]);
}

// ---------------------------------------------------------------------------
// Bucket pass 1: exclusive scan of 782 bucket counts (single 1024-thr block).
// ---------------------------------------------------------------------------
__global__ void bscan_kernel(const int* __restrict__ bucket_cnt,
                             int* __restrict__ bucket_base,
                             int* __restrict__ bucket_cursor) {
    __shared__ int buf[1024];
    int t = threadIdx.x;
    int v = (t < NB) ? bucket_cnt[t] : 0;
    buf[t] = v;
    __syncthreads();
    for (int off = 1; off < 1024; off <<= 1) {
        int u = (t >= off) ? buf[t - off] : 0;
        __syncthreads();
        buf[t] += u;
        __syncthreads();
    }
    int excl = buf[t] - v;
    if (t < NB) { bucket_base[t] = excl; bucket_cursor[t] = excl; }
    if (t == 0) bucket_base[NB] = N_EDGES;
}

// ---------------------------------------------------------------------------
// Bucket pass 2: two-level scatter into bucket-ordered array. Each block
// reserves contiguous runs per bucket (one global atomic per bucket), so
// writes land as ~10-entry runs -> ~1.5x line amplification instead of 16x.
// Entry packing: src (17 bits) | (dst&127) << 17.
// ---------------------------------------------------------------------------
__global__ void bscatter_kernel(const int* __restrict__ ei,
                                int* __restrict__ bucket_cursor,
                                unsigned* __restrict__ bucketed) {
    __shared__ int lcnt[NB];
    __shared__ int lbase[NB];
    for (int j = threadIdx.x; j < NB; j += 256) lcnt[j] = 0;
    __syncthreads();
    long base = (long)blockIdx.x * EPB;
    for (int k = threadIdx.x; k < EPB; k += 256) {
        long e = base + k;
        if (e < N_EDGES) atomicAdd(&lcnt[ei[N_EDGES + e] >> 7], 1);
    }
    __syncthreads();
    for (int j = threadIdx.x; j < NB; j += 256) {
        int c = lcnt[j];
        lbase[j] = c ? atomicAdd(&bucket_cursor[j], c) : 0;
        lcnt[j] = 0;
    }
    __syncthreads();
    for (int k = threadIdx.x; k < EPB; k += 256) {
        long e = base + k;
        if (e >= N_EDGES) continue;
        int d = ei[N_EDGES + e], s = ei[e];
        int b = d >> 7;
        int off = atomicAdd(&lcnt[b], 1);
        bucketed[lbase[b] + off] = (unsigned)s | ((unsigned)(d & 127) << 17);
    }
}

// ---------------------------------------------------------------------------
// Bucket pass 3: one block per bucket. LDS hist+scan of the 128 local nodes
// -> row_start; then scatter src into csr_src within the bucket's ~8KB
// region (L2-resident, no write amplification).
// ---------------------------------------------------------------------------
__global__ void bfinal_kernel(const unsigned* __restrict__ bucketed,
                              const int* __restrict__ bucket_base,
                              int* __restrict__ row_start,
                              int* __restrict__ csr_src) {
    __shared__ int cnt[128];
    __shared__ int pre[129];
    int t = threadIdx.x, b = blockIdx.x;
    if (t < 128) cnt[t] = 0;
    __syncthreads();
    int bb = bucket_base[b], be = bucket_base[b + 1];
    for (int k = bb + t; k < be; k += 256) atomicAdd(&cnt[bucketed[k] >> 17], 1);
    __syncthreads();
    if (t < 128) pre[t + 1] = cnt[t];
    if (t == 0) pre[0] = 0;
    __syncthreads();
    for (int off = 1; off < 129; off <<= 1) {
        int u = (t >= off && t <= 128) ? pre[t - off] : 0;
        __syncthreads();
        if (t >= off && t <= 128) pre[t] += u;
        __syncthreads();
    }
    if (t <= 128) {
        long gid = (long)b * 128 + t;
        if (gid <= N_NODES) row_start[gid] = bb + pre[t];
    }
    if (t < 128) cnt[t] = pre[t];  // reuse as local cursor
    __syncthreads();
    for (int k = bb + t; k < be; k += 256) {
        unsigned u = bucketed[k];
        int dl = (int)(u >> 17);
        int pos = atomicAdd(&cnt[dl], 1);
        csr_src[bb + pos] = (int)(u & 0x1FFFFu);
    }
}

// ---------------------------------------------------------------------------
// fp32 -> bf16 (RNE) copy of the node features: 256B rows become 128B.
// ---------------------------------------------------------------------------
__device__ __forceinline__ unsigned short f2b(float f) {
    unsigned u = __float_as_uint(f);
    unsigned r = u + 0x7FFFu + ((u >> 16) & 1u);
    return (unsigned short)(r >> 16);
}
__global__ void to_bf16_kernel(const float* __restrict__ x,
                               unsigned short* __restrict__ xb) {
    long tid = (long)blockIdx.x * blockDim.x + threadIdx.x;
    if (tid >= (long)N_NODES * 16) return;
    float4 v = reinterpret_cast<const float4*>(x)[tid];
    ushort4 o;
    o.x = f2b(v.x); o.y = f2b(v.y); o.z = f2b(v.z); o.w = f2b(v.w);
    reinterpret_cast<ushort4*>(xb)[tid] = o;
}

// ---------------------------------------------------------------------------
// Gather: h[i] = x_fp32[i] + sum_{j->i} xb_bf16[j]. 16 threads/node.
// 4-way unrolled with independent accumulators for memory-level parallelism.
// ---------------------------------------------------------------------------
__device__ __forceinline__ void bacc(float4& a, ushort4 v) {
    a.x += __uint_as_float((unsigned)v.x << 16);
    a.y += __uint_as_float((unsigned)v.y << 16);
    a.z += __uint_as_float((unsigned)v.z << 16);
    a.w += __uint_as_float((unsigned)v.w << 16);
}
__global__ void gather_kernel(const float* __restrict__ x,
                              const unsigned short* __restrict__ xb,
                              const int* __restrict__ row_start,
                              const int* __restrict__ csr_src,
                              float* __restrict__ h) {
    long tid = (long)blockIdx.x * blockDim.x + threadIdx.x;
    int i = (int)(tid >> 4);
    if (i >= N_NODES) return;
    int f4 = (int)tid & 15;
    const ushort4* xb4 = reinterpret_cast<const ushort4*>(xb);
    float4 a0 = reinterpret_cast<const float4*>(x)[(long)i * 16 + f4];  // self, fp32
    float4 a1{0.f,0.f,0.f,0.f}, a2{0.f,0.f,0.f,0.f}, a3{0.f,0.f,0.f,0.f};
    int e = row_start[i], end = row_start[i + 1];
    for (; e + 4 <= end; e += 4) {
        int s0 = csr_src[e], s1 = csr_src[e+1], s2 = csr_src[e+2], s3 = csr_src[e+3];
        ushort4 v0 = xb4[(long)s0 * 16 + f4];
        ushort4 v1 = xb4[(long)s1 * 16 + f4];
        ushort4 v2 = xb4[(long)s2 * 16 + f4];
        ushort4 v3 = xb4[(long)s3 * 16 + f4];
        bacc(a0, v0); bacc(a1, v1); bacc(a2, v2); bacc(a3, v3);
    }
    for (; e < end; e++) bacc(a0, xb4[(long)csr_src[e] * 16 + f4]);
    a0.x += a1.x + a2.x + a3.x;
    a0.y += a1.y + a2.y + a3.y;
    a0.z += a1.z + a2.z + a3.z;
    a0.w += a1.w + a2.w + a3.w;
    reinterpret_cast<float4*>(h)[(long)i * 16 + f4] = a0;
}

// ---------------------------------------------------------------------------
// LDS-tiled MLP GEMM (unchanged from round 3): out = relu(in @ W).
// ---------------------------------------------------------------------------
template <int K, int NOUT>
__global__ __launch_bounds__(256) void mlp_tiled(const float* __restrict__ in,
                                                 const float* __restrict__ W,
                                                 float* __restrict__ outp,
                                                 int n_nodes) {
    constexpr int PAD = 4;
    constexpr int CG = NOUT / 64;
    __shared__ float As[64][K + PAD];
    __shared__ float Ws[K][NOUT];

    int tid = threadIdx.x;
    int base = blockIdx.x * 64;

    const float4* in4 = reinterpret_cast<const float4*>(in);
    for (int q = tid; q < 64 * (K / 4); q += 256) {
        int row = q / (K / 4), c4 = q % (K / 4);
        int gr = base + row;
        float4 v = float4{0.f, 0.f, 0.f, 0.f};
        if (gr < n_nodes) v = in4[(long)gr * (K / 4) + c4];
        *reinterpret_cast<float4*>(&As[row][c4 * 4]) = v;
    }
    const float4* W4 = reinterpret_cast<const float4*>(W);
    float4* Ws4 = reinterpret_cast<float4*>(&Ws[0][0]);
    for (int q = tid; q < K * NOUT / 4; q += 256) Ws4[q] = W4[q];
    __syncthreads();

    int tx = tid & 15, ty = tid >> 4;
    float acc[4][CG * 4];
#pragma unroll
    for (int i = 0; i < 4; i++)
#pragma unroll
        for (int c = 0; c < CG * 4; c++) acc[i][c] = 0.f;

    for (int k4 = 0; k4 < K / 4; k4++) {
        float4 a[4];
#pragma unroll
        for (int i = 0; i < 4; i++)
            a[i] = *reinterpret_cast<const float4*>(&As[ty * 4 + i][k4 * 4]);
#pragma unroll
        for (int kk = 0; kk < 4; kk++) {
            int k = k4 * 4 + kk;
#pragma unroll
            for (int g = 0; g < CG; g++) {
                float4 w = *reinterpret_cast<const float4*>(&Ws[k][g * 64 + tx * 4]);
#pragma unroll
                for (int i = 0; i < 4; i++) {
                    float av = (kk == 0) ? a[i].x : (kk == 1) ? a[i].y
                             : (kk == 2) ? a[i].z : a[i].w;
                    acc[i][g * 4 + 0] += av * w.x;
                    acc[i][g * 4 + 1] += av * w.y;
                    acc[i][g * 4 + 2] += av * w.z;
                    acc[i][g * 4 + 3] += av * w.w;
                }
            }
        }
    }

#pragma unroll
    for (int i = 0; i < 4; i++) {
        int gr = base + ty * 4 + i;
        if (gr >= n_nodes) continue;
#pragma unroll
        for (int g = 0; g < CG; g++) {
            float4 o;
            o.x = fmaxf(acc[i][g * 4 + 0], 0.f);
            o.y = fmaxf(acc[i][g * 4 + 1], 0.f);
            o.z = fmaxf(acc[i][g * 4 + 2], 0.f);
            o.w = fmaxf(acc[i][g * 4 + 3], 0.f);
            *reinterpret_cast<float4*>(outp + (long)gr * NOUT + g * 64 + tx * 4) = o;
        }
    }
}

// ---------------------------------------------------------------------------
// Global add-pool over sorted batch (unchanged).
// ---------------------------------------------------------------------------
__global__ void pool_kernel(const float* __restrict__ x,
                            const int* __restrict__ batch,
                            float* __restrict__ pooled) {
    int tid = blockIdx.x * blockDim.x + threadIdx.x;
    int chunk = tid >> 4;
    int base = chunk * 16;
    if (base >= N_NODES) return;
    int f4 = tid & 15;
    int endn = min(base + 16, N_NODES);
    const float4* x4 = reinterpret_cast<const float4*>(x);
    float4 acc{0.f, 0.f, 0.f, 0.f};
    int curg = batch[base];
    for (int i = base; i < endn; i++) {
        int g = batch[i];
        if (g != curg) {
            float* p = pooled + (long)curg * NF + f4 * 4;
            unsafeAtomicAdd(p + 0, acc.x); unsafeAtomicAdd(p + 1, acc.y);
            unsafeAtomicAdd(p + 2, acc.z); unsafeAtomicAdd(p + 3, acc.w);
            acc = float4{0.f, 0.f, 0.f, 0.f};
            curg = g;
        }
        float4 v = x4[(long)i * 16 + f4];
        acc.x += v.x; acc.y += v.y; acc.z += v.z; acc.w += v.w;
    }
    float* p = pooled + (long)curg * NF + f4 * 4;
    unsafeAtomicAdd(p + 0, acc.x); unsafeAtomicAdd(p + 1, acc.y);
    unsafeAtomicAdd(p + 2, acc.z); unsafeAtomicAdd(p + 3, acc.w);
}

// ---------------------------------------------------------------------------
// Head (unchanged).
// ---------------------------------------------------------------------------
__global__ void head_kernel(const float* __restrict__ pooled,
                            const float* __restrict__ fcW,
                            const float* __restrict__ fcb,
                            float* __restrict__ out) {
    int g = blockIdx.x * blockDim.x + threadIdx.x;
    if (g >= NG) return;
    float p[NF];
    const float4* pi = reinterpret_cast<const float4*>(pooled + (long)g * NF);
#pragma unroll
    for (int q = 0; q < NF / 4; q++) {
        float4 a = pi[q];
        p[4 * q + 0] = a.x; p[4 * q + 1] = a.y;
        p[4 * q + 2] = a.z; p[4 * q + 3] = a.w;
    }
    float lg[NC];
#pragma unroll
    for (int c = 0; c < NC; c++) {
        float acc = fcb[c];
#pragma unroll
        for (int k = 0; k < NF; k++) acc += p[k] * fcW[k * NC + c];
        lg[c] = acc;
    }
    float m = lg[0];
#pragma unroll
    for (int c = 1; c < NC; c++) m = fmaxf(m, lg[c]);
    float s = 0.f;
#pragma unroll
    for (int c = 0; c < NC; c++) s += expf(lg[c] - m);
    float ls = logf(s);
#pragma unroll
    for (int c = 0; c < NC; c++) out[(long)g * NC + c] = lg[c] - m - ls;
}

extern "C" void kernel_launch(void* const* d_in, const int* in_sizes, int n_in,
                              void* d_out, int out_size, void* d_ws, size_t ws_size,
                              hipStream_t stream) {
    const float* x   = (const float*)d_in[0];
    const float* W1  = (const float*)d_in[1];
    const float* W2  = (const float*)d_in[2];
    const float* fcW = (const float*)d_in[3];
    const float* fcb = (const float*)d_in[4];
    const int* ei    = (const int*)d_in[5];
    const int* batch = (const int*)d_in[6];
    float* out = (float*)d_out;

    // Workspace layout (~109.3 MB):
    //   A [N,64] fp32 | H [N,64] fp32 | U(51.2MB union):
    //     { T [N,128] fp32 }  <- alive mlp1->mlp2
    //     { xb [N,64] bf16 }  <- alive to_bf16->gather
    //     { bucket_cnt/base/cursor + bucketed[E] } <- alive CSR build only
    //   pooled [512,64] | row_start[N+1 pad] | csr_src[E]
    float* A = (float*)d_ws;
    float* H = A + (size_t)N_NODES * NF;
    float* T = H + (size_t)N_NODES * NF;
    unsigned short* xb = (unsigned short*)T;
    int* bU = (int*)T;
    int* bucket_cnt    = bU;                    // 784
    int* bucket_base   = bU + 784;              // 788
    int* bucket_cursor = bU + 784 + 788;        // 784
    unsigned* bucketed = (unsigned*)(bU + 784 + 788 + 784);  // E
    float* pooled  = T + (size_t)N_NODES * 2 * NF;
    int* row_start = (int*)(pooled + (size_t)NG * NF);       // 100004 (padded)
    int* csr_src   = row_start + 100004;                     // E

    const int nblk_e = (N_EDGES + EPB - 1) / EPB;  // 196

    // ---- CSR build: bucketed counting sort by dst ----
    hipMemsetAsync(bucket_cnt, 0, 784 * sizeof(int), stream);
    bhist_kernel<<<nblk_e, 256, 0, stream>>>(ei, bucket_cnt);
    bscan_kernel<<<1, 1024, 0, stream>>>(bucket_cnt, bucket_base, bucket_cursor);
    bscatter_kernel<<<nblk_e, 256, 0, stream>>>(ei, bucket_cursor, bucketed);
    bfinal_kernel<<<NB, 256, 0, stream>>>(bucketed, bucket_base, row_start, csr_src);

    // ---- 4 GIN layers ----
    const int mlp_blocks = (N_NODES + 63) / 64;
    const int g_blocks = (N_NODES * 16 + 255) / 256;
    const float* cur = x;
    for (int l = 0; l < NL; l++) {
        to_bf16_kernel<<<g_blocks, 256, 0, stream>>>(cur, xb);
        gather_kernel<<<g_blocks, 256, 0, stream>>>(cur, xb, row_start, csr_src, H);
        mlp_tiled<NF, 2 * NF><<<mlp_blocks, 256, 0, stream>>>(
            H, W1 + (size_t)l * NF * 2 * NF, T, N_NODES);
        mlp_tiled<2 * NF, NF><<<mlp_blocks, 256, 0, stream>>>(
            T, W2 + (size_t)l * 2 * NF * NF, A, N_NODES);
        cur = A;
    }

    // ---- pool + head ----
    hipMemsetAsync(pooled, 0, (size_t)NG * NF * sizeof(float), stream);
    pool_kernel<<<(N_NODES + 255) / 256, 256, 0, stream>>>(cur, batch, pooled);
    head_kernel<<<(NG + 255) / 256, 256, 0, stream>>>(pooled, fcW, fcb, out);
}